// Round 4
// baseline (63.959 us; speedup 1.0000x reference)
//
#include <hip/hip_runtime.h>

#define NROWS 4096
#define DIM   512
#define MARGIN 0.3f

typedef _Float16 f16;
typedef _Float16 f16x8 __attribute__((ext_vector_type(8)));
typedef float    f32x4 __attribute__((ext_vector_type(4)));

// ---------------- prep: norms + fp32->fp16 tiled convert + init ----------------
// Xh layout: tile (R,K0), R=row/128 in [0,32), K0=k/32 in [0,16).
// Tile = 512 units of 16B: unit u = rg*64 + c*16 + r (rg=(row%128)/16, r=row%16)
// element (row, k=K0*32+c*8+j) at half index (tile*512+u)*8 + j.
__global__ void prep_kernel(const float* __restrict__ X,
                            float* __restrict__ norms, f16* __restrict__ Xh,
                            unsigned* __restrict__ hp, unsigned* __restrict__ hn,
                            unsigned* __restrict__ cnt) {
    int t = threadIdx.x;
    int wave = t >> 6, lane = t & 63;
    int row  = blockIdx.x * 4 + wave;
    const float4* p = (const float4*)(X + (size_t)row * DIM + lane * 8);
    float4 a = p[0], b = p[1];
    float s = a.x*a.x + a.y*a.y + a.z*a.z + a.w*a.w
            + b.x*b.x + b.y*b.y + b.z*b.z + b.w*b.w;
    #pragma unroll
    for (int o = 32; o; o >>= 1) s += __shfl_xor(s, o);
    if (lane == 0) norms[row] = s;

    f16x8 h;
    h[0] = (f16)a.x; h[1] = (f16)a.y; h[2] = (f16)a.z; h[3] = (f16)a.w;
    h[4] = (f16)b.x; h[5] = (f16)b.y; h[6] = (f16)b.z; h[7] = (f16)b.w;
    int K0 = lane >> 2, c = lane & 3;
    int R = row >> 7, rw = row & 127, rg = rw >> 4, r = rw & 15;
    size_t unit = (size_t)(R * 16 + K0) * 512 + rg * 64 + c * 16 + r;
    *(f16x8*)(Xh + unit * 8) = h;

    int g = blockIdx.x * 256 + t;
    if (g < NROWS) { hp[g] = 0u; hn[g] = 0x7f800000u; }
    if (g == 0) *cnt = 0u;
}

__device__ inline void gload_lds16(const f16* g, f16* l) {
    __builtin_amdgcn_global_load_lds(
        (const __attribute__((address_space(1))) void*)g,
        (__attribute__((address_space(3))) void*)l, 16, 0, 0);
}

// stage one 128x32 A-tile + B-tile pair into buf; wave w covers units [qb, qb+256)
__device__ inline void stage_tile(const f16* __restrict__ At, const f16* __restrict__ Bt,
                                  f16* buf, int qb, int lane) {
    const f16* base = (qb < 512) ? (At + (size_t)qb * 8) : (Bt + (size_t)(qb - 512) * 8);
    #pragma unroll
    for (int c2 = 0; c2 < 4; ++c2)
        gload_lds16(base + (size_t)(c2 * 64 + lane) * 8, buf + (size_t)(qb + c2 * 64) * 8);
}

// ---------------- MFMA fused GEMM + masked row/col max-min + tail finalize ----------------
__global__ __launch_bounds__(256, 3) void mfma_dist_kernel(
        const f16* __restrict__ Xh, const int* __restrict__ labels,
        const float* __restrict__ norms,
        unsigned* __restrict__ hp, unsigned* __restrict__ hn,
        unsigned* __restrict__ cnt, float* __restrict__ out) {
    __shared__ __align__(16) f16 S0[8192];
    __shared__ __align__(16) f16 S1[8192];
    __shared__ int lastflag;

    const int t    = threadIdx.x;
    const int lane = t & 63, w = t >> 6;
    const int l15  = lane & 15, l4 = lane >> 4;

    // linear block id -> (by <= bx)
    int bt = blockIdx.x;
    int bx = (int)((sqrtf(8.0f * bt + 1.0f) - 1.0f) * 0.5f);
    while ((bx + 1) * (bx + 2) / 2 <= bt) ++bx;
    while (bx * (bx + 1) / 2 > bt) --bx;
    int by = bt - bx * (bx + 1) / 2;

    const int wr = w >> 1, wc = w & 1;
    const int qb = w * 256;

    const f16* Abase = Xh + (size_t)(by * 16) * 4096;
    const f16* Bbase = Xh + (size_t)(bx * 16) * 4096;

    f32x4 zero = {0.f, 0.f, 0.f, 0.f};
    f32x4 acc[4][4];
    #pragma unroll
    for (int m = 0; m < 4; ++m)
        #pragma unroll
        for (int n = 0; n < 4; ++n) acc[m][n] = zero;

    stage_tile(Abase, Bbase, S0, qb, lane);
    __syncthreads();

    #pragma unroll
    for (int kt = 0; kt < 16; ++kt) {
        f16* cur = (kt & 1) ? S1 : S0;
        f16* nxt = (kt & 1) ? S0 : S1;
        if (kt < 15)
            stage_tile(Abase + (size_t)(kt + 1) * 4096,
                       Bbase + (size_t)(kt + 1) * 4096, nxt, qb, lane);
        f16x8 af[4], bf[4];
        #pragma unroll
        for (int m = 0; m < 4; ++m)
            af[m] = *(const f16x8*)&cur[(size_t)((wr * 4 + m) * 64 + l4 * 16 + l15) * 8];
        #pragma unroll
        for (int n = 0; n < 4; ++n)
            bf[n] = *(const f16x8*)&cur[(size_t)(512 + (wc * 4 + n) * 64 + l4 * 16 + l15) * 8];
        #pragma unroll
        for (int m = 0; m < 4; ++m)
            #pragma unroll
            for (int n = 0; n < 4; ++n)
                acc[m][n] = __builtin_amdgcn_mfma_f32_16x16x32_f16(af[m], bf[n], acc[m][n], 0, 0, 0);
        if (kt < 15) __syncthreads();
    }

    // ---- epilogue: sq = ni + nj - 2*dot, masked row & col reduce ----
    const int wrow = by * 128 + wr * 64;
    const int wcol = bx * 128 + wc * 64;
    const float FINF = __uint_as_float(0x7f800000u);

    int lj[4]; float nj[4];
    #pragma unroll
    for (int n = 0; n < 4; ++n) {
        int gc = wcol + n * 16 + l15; lj[n] = labels[gc]; nj[n] = norms[gc];
    }
    int li[16]; float ni[16];
    #pragma unroll
    for (int m = 0; m < 4; ++m)
        #pragma unroll
        for (int r = 0; r < 4; ++r) {
            int gr = wrow + m * 16 + l4 * 4 + r;
            li[m * 4 + r] = labels[gr]; ni[m * 4 + r] = norms[gr];
        }

    float cp[4], cn[4];
    #pragma unroll
    for (int n = 0; n < 4; ++n) { cp[n] = 0.f; cn[n] = FINF; }

    #pragma unroll
    for (int m = 0; m < 4; ++m) {
        #pragma unroll
        for (int r = 0; r < 4; ++r) {
            float rp = 0.f, rn = FINF;
            #pragma unroll
            for (int n = 0; n < 4; ++n) {
                float sq = fmaxf(fmaf(-2.f, acc[m][n][r], ni[m * 4 + r] + nj[n]), 0.f);
                bool same = (li[m * 4 + r] == lj[n]);
                rp = same ? fmaxf(rp, sq) : rp;
                rn = same ? rn : fminf(rn, sq);
                cp[n] = same ? fmaxf(cp[n], sq) : cp[n];
                cn[n] = same ? cn[n] : fminf(cn[n], sq);
            }
            #pragma unroll
            for (int o = 8; o; o >>= 1) {
                rp = fmaxf(rp, __shfl_xor(rp, o));
                rn = fminf(rn, __shfl_xor(rn, o));
            }
            if (l15 == 0) {
                int gr = wrow + m * 16 + l4 * 4 + r;
                atomicMax(&hp[gr], __float_as_uint(rp));
                atomicMin(&hn[gr], __float_as_uint(rn));
            }
        }
    }
    #pragma unroll
    for (int n = 0; n < 4; ++n) {
        float p = cp[n], q = cn[n];
        p = fmaxf(p, __shfl_xor(p, 16)); q = fminf(q, __shfl_xor(q, 16));
        p = fmaxf(p, __shfl_xor(p, 32)); q = fminf(q, __shfl_xor(q, 32));
        if (l4 == 0) {
            int gc = wcol + n * 16 + l15;
            atomicMax(&hp[gc], __float_as_uint(p));
            atomicMin(&hn[gc], __float_as_uint(q));
        }
    }

    // ---- tail-block fused finalize (last of gridDim blocks) ----
    __threadfence();
    if (t == 0) lastflag = (atomicAdd(cnt, 1u) == gridDim.x - 1) ? 1 : 0;
    __syncthreads();
    if (lastflag == 0) return;

    int* hist = (int*)S0;            // reuse LDS (all GEMM use done)
    hist[t] = 0;
    __syncthreads();
    {
        const int4* lab4 = (const int4*)labels;
        #pragma unroll
        for (int jj = 0; jj < 4; ++jj) {
            int4 lb = lab4[t * 4 + jj];
            atomicAdd(&hist[lb.x], 1); atomicAdd(&hist[lb.y], 1);
            atomicAdd(&hist[lb.z], 1); atomicAdd(&hist[lb.w], 1);
        }
    }
    __syncthreads();
    float v = 0.f;
    #pragma unroll
    for (int j = 0; j < 16; ++j) {
        int i = j * 256 + t;
        unsigned hpv = __hip_atomic_load(&hp[i], __ATOMIC_RELAXED, __HIP_MEMORY_SCOPE_AGENT);
        unsigned hnv = __hip_atomic_load(&hn[i], __ATOMIC_RELAXED, __HIP_MEMORY_SCOPE_AGENT);
        if (hist[labels[i]] > 1) {
            float d = sqrtf(__uint_as_float(hpv)) - sqrtf(__uint_as_float(hnv)) + MARGIN;
            v += fmaxf(d, 0.f);
        }
    }
    #pragma unroll
    for (int o = 32; o; o >>= 1) v += __shfl_xor(v, o);
    float* wsum = (float*)(S0 + 512);
    if ((t & 63) == 0) wsum[t >> 6] = v;
    __syncthreads();
    if (t == 0) out[0] = (wsum[0] + wsum[1] + wsum[2] + wsum[3]) / (float)NROWS;
}

// ---------------- fp32 fallback path (ws too small for Xh) ----------------
__global__ void norms_init_kernel(const float* __restrict__ X,
                                  float* __restrict__ norms,
                                  unsigned* __restrict__ hp, unsigned* __restrict__ hn) {
    int wave = threadIdx.x >> 6;
    int lane = threadIdx.x & 63;
    int row  = blockIdx.x * 4 + wave;
    const float4* xr = (const float4*)(X + (size_t)row * DIM);
    float4 a = xr[lane];
    float4 b = xr[lane + 64];
    float s = a.x*a.x + a.y*a.y + a.z*a.z + a.w*a.w
            + b.x*b.x + b.y*b.y + b.z*b.z + b.w*b.w;
    #pragma unroll
    for (int o = 32; o; o >>= 1) s += __shfl_xor(s, o);
    if (lane == 0) norms[row] = s;
    int g = blockIdx.x * 256 + threadIdx.x;
    if (g < NROWS) { hp[g] = 0u; hn[g] = 0x7f800000u; }
}

#define BK  32
#define PAD 68
__global__ __launch_bounds__(256) void dist_fp32_kernel(
        const float* __restrict__ X, const int* __restrict__ labels,
        const float* __restrict__ norms,
        unsigned* __restrict__ hp, unsigned* __restrict__ hn) {
    __shared__ __align__(16) float As[BK][PAD];
    __shared__ __align__(16) float Bs[BK][PAD];
    const int t  = threadIdx.x;
    const int tx = t & 15, ty = t >> 4;
    const int row0 = blockIdx.y * 64, col0 = blockIdx.x * 64;

    float acc[4][4] = {};
    for (int k0 = 0; k0 < DIM; k0 += BK) {
        #pragma unroll
        for (int l = 0; l < 2; ++l) {
            int idx = t + l * 256;
            int r = idx >> 3, fc = idx & 7;
            float4 va = *(const float4*)(X + (size_t)(row0 + r) * DIM + k0 + fc * 4);
            float4 vb = *(const float4*)(X + (size_t)(col0 + r) * DIM + k0 + fc * 4);
            As[fc*4+0][r] = va.x; As[fc*4+1][r] = va.y;
            As[fc*4+2][r] = va.z; As[fc*4+3][r] = va.w;
            Bs[fc*4+0][r] = vb.x; Bs[fc*4+1][r] = vb.y;
            Bs[fc*4+2][r] = vb.z; Bs[fc*4+3][r] = vb.w;
        }
        __syncthreads();
        #pragma unroll
        for (int kk = 0; kk < BK; ++kk) {
            float4 a = *(const float4*)&As[kk][ty * 4];
            float4 b = *(const float4*)&Bs[kk][tx * 4];
            float av[4] = {a.x, a.y, a.z, a.w};
            float bv[4] = {b.x, b.y, b.z, b.w};
            #pragma unroll
            for (int m = 0; m < 4; ++m)
                #pragma unroll
                for (int n = 0; n < 4; ++n)
                    acc[m][n] = fmaf(av[m], bv[n], acc[m][n]);
        }
        __syncthreads();
    }
    int li[4], lj[4]; float ni[4], nj[4];
    #pragma unroll
    for (int m = 0; m < 4; ++m) {
        int gi = row0 + ty * 4 + m; li[m] = labels[gi]; ni[m] = norms[gi];
    }
    #pragma unroll
    for (int n = 0; n < 4; ++n) {
        int gj = col0 + tx * 4 + n; lj[n] = labels[gj]; nj[n] = norms[gj];
    }
    #pragma unroll
    for (int m = 0; m < 4; ++m) {
        float pmax = 0.0f;
        float nmin = __uint_as_float(0x7f800000u);
        #pragma unroll
        for (int n = 0; n < 4; ++n) {
            float sq = fmaxf(ni[m] + nj[n] - 2.0f * acc[m][n], 0.0f);
            if (li[m] == lj[n]) pmax = fmaxf(pmax, sq);
            else                nmin = fminf(nmin, sq);
        }
        #pragma unroll
        for (int o = 8; o; o >>= 1) {
            pmax = fmaxf(pmax, __shfl_xor(pmax, o));
            nmin = fminf(nmin, __shfl_xor(nmin, o));
        }
        if (tx == 0) {
            int gi = row0 + ty * 4 + m;
            atomicMax(&hp[gi], __float_as_uint(pmax));
            atomicMin(&hn[gi], __float_as_uint(nmin));
        }
    }
}

__global__ __launch_bounds__(1024) void finalize_kernel(
        const unsigned* __restrict__ hp, const unsigned* __restrict__ hn,
        const int* __restrict__ labels, float* __restrict__ out) {
    __shared__ int hist[256];
    __shared__ float wsum[16];
    int t = threadIdx.x;
    if (t < 256) hist[t] = 0;
    __syncthreads();
    int4 lab = ((const int4*)labels)[t];
    atomicAdd(&hist[lab.x], 1); atomicAdd(&hist[lab.y], 1);
    atomicAdd(&hist[lab.z], 1); atomicAdd(&hist[lab.w], 1);
    __syncthreads();
    uint4 hp4 = ((const uint4*)hp)[t];
    uint4 hn4 = ((const uint4*)hn)[t];
    int      lv[4]  = {lab.x, lab.y, lab.z, lab.w};
    unsigned hpv[4] = {hp4.x, hp4.y, hp4.z, hp4.w};
    unsigned hnv[4] = {hn4.x, hn4.y, hn4.z, hn4.w};
    float v = 0.f;
    #pragma unroll
    for (int j = 0; j < 4; ++j) {
        float hpd = sqrtf(__uint_as_float(hpv[j]));
        float hnd = sqrtf(__uint_as_float(hnv[j]));
        if (hist[lv[j]] > 1) v += fmaxf(hpd - hnd + MARGIN, 0.f);
    }
    #pragma unroll
    for (int o = 32; o; o >>= 1) v += __shfl_xor(v, o);
    int lane = t & 63, wv = t >> 6;
    if (lane == 0) wsum[wv] = v;
    __syncthreads();
    if (t == 0) {
        float s = 0.f;
        #pragma unroll
        for (int i = 0; i < 16; ++i) s += wsum[i];
        out[0] = s / (float)NROWS;
    }
}

extern "C" void kernel_launch(void* const* d_in, const int* in_sizes, int n_in,
                              void* d_out, int out_size, void* d_ws, size_t ws_size,
                              hipStream_t stream) {
    const float* X      = (const float*)d_in[0];
    const int*   labels = (const int*)d_in[1];
    float* ws = (float*)d_ws;
    // ws (floats): norms[4096] | hp[4096] | hn[4096] | cnt | pad -> 64KB | Xh (4MB)
    float*    norms = ws;
    unsigned* hp    = (unsigned*)(ws + 4096);
    unsigned* hn    = (unsigned*)(ws + 8192);
    unsigned* cnt   = (unsigned*)(ws + 12288);
    f16*      Xh    = (f16*)((char*)d_ws + 65536);
    float*    out   = (float*)d_out;

    const size_t need = 65536 + (size_t)NROWS * DIM * sizeof(f16);

    if (ws_size >= need) {
        hipLaunchKernelGGL(prep_kernel, dim3(NROWS/4), dim3(256), 0, stream,
                           X, norms, Xh, hp, hn, cnt);
        hipLaunchKernelGGL(mfma_dist_kernel, dim3(528), dim3(256), 0, stream,
                           Xh, labels, norms, hp, hn, cnt, out);
    } else {
        hipLaunchKernelGGL(norms_init_kernel, dim3(NROWS/4), dim3(256), 0, stream, X, norms, hp, hn);
        hipLaunchKernelGGL(dist_fp32_kernel, dim3(64, 64), dim3(256), 0, stream, X, labels, norms, hp, hn);
        hipLaunchKernelGGL(finalize_kernel, dim3(1), dim3(1024), 0, stream, hp, hn, labels, out);
    }
}

// Round 5
// 39.484 us; speedup vs baseline: 1.6198x; 1.6198x over previous
//
#include <hip/hip_runtime.h>

#define NROWS 4096
#define DIM   512
#define MARGIN 0.3f

typedef _Float16 f16;
typedef _Float16 f16x8 __attribute__((ext_vector_type(8)));
typedef float    f32x4 __attribute__((ext_vector_type(4)));

// ---------------- per-row squared norms (fp32) + hp/hn init ----------------
__global__ void norms_init_kernel(const float* __restrict__ X,
                                  float* __restrict__ norms,
                                  unsigned* __restrict__ hp, unsigned* __restrict__ hn) {
    int wave = threadIdx.x >> 6;
    int lane = threadIdx.x & 63;
    int row  = blockIdx.x * 4 + wave;
    const float4* xr = (const float4*)(X + (size_t)row * DIM);
    float4 a = xr[lane];
    float4 b = xr[lane + 64];
    float s = a.x*a.x + a.y*a.y + a.z*a.z + a.w*a.w
            + b.x*b.x + b.y*b.y + b.z*b.z + b.w*b.w;
    #pragma unroll
    for (int o = 32; o; o >>= 1) s += __shfl_xor(s, o);
    if (lane == 0) norms[row] = s;
    int g = blockIdx.x * 256 + threadIdx.x;
    if (g < NROWS) { hp[g] = 0u; hn[g] = 0x7f800000u; }
}

// ---------------- fp32 -> fp16 in MFMA-tiled layout (coalesced writes) ----------------
// Xh layout: tile (R,K0), R=row/128 in [0,32), K0=k/32 in [0,16).
// Tile = 512 units of 16B: unit u = rg*64 + c*16 + r (rg=(row%128)/16, r=row%16)
// element (row, k=K0*32+c*8+j) at half index (tile*512+u)*8 + j.
__global__ void convert_kernel(const float* __restrict__ X, f16* __restrict__ Xh) {
    int g = blockIdx.x * 256 + threadIdx.x;         // [0, 262144) units
    int tile = g >> 9, u = g & 511;
    int R = tile >> 4, K0 = tile & 15;
    int rg = u >> 6, c = (u >> 4) & 3, r = u & 15;
    int row = R * 128 + rg * 16 + r;
    int k0  = K0 * 32 + c * 8;
    const float4* p = (const float4*)(X + (size_t)row * DIM + k0);
    float4 a = p[0], b = p[1];
    f16x8 h;
    h[0] = (f16)a.x; h[1] = (f16)a.y; h[2] = (f16)a.z; h[3] = (f16)a.w;
    h[4] = (f16)b.x; h[5] = (f16)b.y; h[6] = (f16)b.z; h[7] = (f16)b.w;
    *(f16x8*)(Xh + (size_t)g * 8) = h;
}

__device__ inline void gload_lds16(const f16* g, f16* l) {
    __builtin_amdgcn_global_load_lds(
        (const __attribute__((address_space(1))) void*)g,
        (__attribute__((address_space(3))) void*)l, 16, 0, 0);
}

// stage one 128x32 A-tile + B-tile pair into buf; wave w covers units [qb, qb+256)
__device__ inline void stage_tile(const f16* __restrict__ At, const f16* __restrict__ Bt,
                                  f16* buf, int qb, int lane) {
    const f16* base = (qb < 512) ? (At + (size_t)qb * 8) : (Bt + (size_t)(qb - 512) * 8);
    #pragma unroll
    for (int c2 = 0; c2 < 4; ++c2)
        gload_lds16(base + (size_t)(c2 * 64 + lane) * 8, buf + (size_t)(qb + c2 * 64) * 8);
}

// ---------------- MFMA fused GEMM + masked row/col max-min ----------------
// Lower-triangle grid (by <= bx); 128x128 tile, 4 waves. Counted-vmcnt
// double-buffered pipeline: tile kt+2 staged right after the "buf free"
// barrier; in-loop waits are vmcnt(4) (one tile still in flight), never 0.
__global__ __launch_bounds__(256, 3) void mfma_dist_kernel(
        const f16* __restrict__ Xh, const int* __restrict__ labels,
        const float* __restrict__ norms,
        unsigned* __restrict__ hp, unsigned* __restrict__ hn) {
    __shared__ __align__(16) f16 S0[8192];
    __shared__ __align__(16) f16 S1[8192];

    const int t    = threadIdx.x;
    const int lane = t & 63, w = t >> 6;
    const int l15  = lane & 15, l4 = lane >> 4;

    // XCD chunk swizzle: 528 = 8 * 66 exactly -> bijective remap so each XCD
    // gets a contiguous run of triangle ids (panel working set fits its L2).
    int bthw = blockIdx.x;
    int bt = (bthw & 7) * 66 + (bthw >> 3);

    // linear bt -> (by <= bx)
    int bx = (int)((sqrtf(8.0f * bt + 1.0f) - 1.0f) * 0.5f);
    while ((bx + 1) * (bx + 2) / 2 <= bt) ++bx;
    while (bx * (bx + 1) / 2 > bt) --bx;
    int by = bt - bx * (bx + 1) / 2;

    const int wr = w >> 1, wc = w & 1;
    const int qb = w * 256;

    const f16* Abase = Xh + (size_t)(by * 16) * 4096;
    const f16* Bbase = Xh + (size_t)(bx * 16) * 4096;

    f32x4 zero = {0.f, 0.f, 0.f, 0.f};
    f32x4 acc[4][4];
    #pragma unroll
    for (int m = 0; m < 4; ++m)
        #pragma unroll
        for (int n = 0; n < 4; ++n) acc[m][n] = zero;

    // prologue: two tiles in flight
    stage_tile(Abase,        Bbase,        S0, qb, lane);
    stage_tile(Abase + 4096, Bbase + 4096, S1, qb, lane);
    __builtin_amdgcn_sched_barrier(0);

    #pragma unroll
    for (int kt = 0; kt < 16; ++kt) {
        f16* cur = (kt & 1) ? S1 : S0;
        // wait for tile kt (oldest 4 loads); keep kt+1's 4 in flight
        if (kt == 15) asm volatile("s_waitcnt vmcnt(0)" ::: "memory");
        else          asm volatile("s_waitcnt vmcnt(4)" ::: "memory");
        __builtin_amdgcn_s_barrier();          // tile kt ready for all waves
        __builtin_amdgcn_sched_barrier(0);

        f16x8 af[4], bf[4];
        #pragma unroll
        for (int m = 0; m < 4; ++m)
            af[m] = *(const f16x8*)&cur[(size_t)((wr * 4 + m) * 64 + l4 * 16 + l15) * 8];
        #pragma unroll
        for (int n = 0; n < 4; ++n)
            bf[n] = *(const f16x8*)&cur[(size_t)(512 + (wc * 4 + n) * 64 + l4 * 16 + l15) * 8];
        asm volatile("s_waitcnt lgkmcnt(0)" ::: "memory");
        __builtin_amdgcn_sched_barrier(0);
        __builtin_amdgcn_s_barrier();          // all waves done reading cur
        __builtin_amdgcn_sched_barrier(0);

        if (kt + 2 < 16)                       // refill cur with tile kt+2
            stage_tile(Abase + (size_t)(kt + 2) * 4096,
                       Bbase + (size_t)(kt + 2) * 4096, cur, qb, lane);
        __builtin_amdgcn_sched_barrier(0);

        #pragma unroll
        for (int m = 0; m < 4; ++m)
            #pragma unroll
            for (int n = 0; n < 4; ++n)
                acc[m][n] = __builtin_amdgcn_mfma_f32_16x16x32_f16(af[m], bf[n], acc[m][n], 0, 0, 0);
        __builtin_amdgcn_sched_barrier(0);
    }

    // ---- epilogue: sq = ni + nj - 2*dot, masked row & col reduce ----
    const int wrow = by * 128 + wr * 64;
    const int wcol = bx * 128 + wc * 64;
    const float FINF = __uint_as_float(0x7f800000u);

    int lj[4]; float nj[4];
    #pragma unroll
    for (int n = 0; n < 4; ++n) {
        int gc = wcol + n * 16 + l15; lj[n] = labels[gc]; nj[n] = norms[gc];
    }
    int li[16]; float ni[16];
    #pragma unroll
    for (int m = 0; m < 4; ++m)
        #pragma unroll
        for (int r = 0; r < 4; ++r) {
            int gr = wrow + m * 16 + l4 * 4 + r;
            li[m * 4 + r] = labels[gr]; ni[m * 4 + r] = norms[gr];
        }

    float cp[4], cn[4];
    #pragma unroll
    for (int n = 0; n < 4; ++n) { cp[n] = 0.f; cn[n] = FINF; }

    #pragma unroll
    for (int m = 0; m < 4; ++m) {
        #pragma unroll
        for (int r = 0; r < 4; ++r) {
            float rp = 0.f, rn = FINF;
            #pragma unroll
            for (int n = 0; n < 4; ++n) {
                float sq = fmaxf(fmaf(-2.f, acc[m][n][r], ni[m * 4 + r] + nj[n]), 0.f);
                bool same = (li[m * 4 + r] == lj[n]);
                rp = same ? fmaxf(rp, sq) : rp;
                rn = same ? rn : fminf(rn, sq);
                cp[n] = same ? fmaxf(cp[n], sq) : cp[n];
                cn[n] = same ? cn[n] : fminf(cn[n], sq);
            }
            #pragma unroll
            for (int o = 8; o; o >>= 1) {
                rp = fmaxf(rp, __shfl_xor(rp, o));
                rn = fminf(rn, __shfl_xor(rn, o));
            }
            if (l15 == 0) {
                int gr = wrow + m * 16 + l4 * 4 + r;
                atomicMax(&hp[gr], __float_as_uint(rp));
                atomicMin(&hn[gr], __float_as_uint(rn));
            }
        }
    }
    #pragma unroll
    for (int n = 0; n < 4; ++n) {
        float p = cp[n], q = cn[n];
        p = fmaxf(p, __shfl_xor(p, 16)); q = fminf(q, __shfl_xor(q, 16));
        p = fmaxf(p, __shfl_xor(p, 32)); q = fminf(q, __shfl_xor(q, 32));
        if (l4 == 0) {
            int gc = wcol + n * 16 + l15;
            atomicMax(&hp[gc], __float_as_uint(p));
            atomicMin(&hn[gc], __float_as_uint(q));
        }
    }
}

// ---------------- fp32 fallback path (ws too small for Xh) ----------------
#define BK  32
#define PAD 68
__global__ __launch_bounds__(256) void dist_fp32_kernel(
        const float* __restrict__ X, const int* __restrict__ labels,
        const float* __restrict__ norms,
        unsigned* __restrict__ hp, unsigned* __restrict__ hn) {
    __shared__ __align__(16) float As[BK][PAD];
    __shared__ __align__(16) float Bs[BK][PAD];
    const int t  = threadIdx.x;
    const int tx = t & 15, ty = t >> 4;
    const int row0 = blockIdx.y * 64, col0 = blockIdx.x * 64;

    float acc[4][4] = {};
    for (int k0 = 0; k0 < DIM; k0 += BK) {
        #pragma unroll
        for (int l = 0; l < 2; ++l) {
            int idx = t + l * 256;
            int r = idx >> 3, fc = idx & 7;
            float4 va = *(const float4*)(X + (size_t)(row0 + r) * DIM + k0 + fc * 4);
            float4 vb = *(const float4*)(X + (size_t)(col0 + r) * DIM + k0 + fc * 4);
            As[fc*4+0][r] = va.x; As[fc*4+1][r] = va.y;
            As[fc*4+2][r] = va.z; As[fc*4+3][r] = va.w;
            Bs[fc*4+0][r] = vb.x; Bs[fc*4+1][r] = vb.y;
            Bs[fc*4+2][r] = vb.z; Bs[fc*4+3][r] = vb.w;
        }
        __syncthreads();
        #pragma unroll
        for (int kk = 0; kk < BK; ++kk) {
            float4 a = *(const float4*)&As[kk][ty * 4];
            float4 b = *(const float4*)&Bs[kk][tx * 4];
            float av[4] = {a.x, a.y, a.z, a.w};
            float bv[4] = {b.x, b.y, b.z, b.w};
            #pragma unroll
            for (int m = 0; m < 4; ++m)
                #pragma unroll
                for (int n = 0; n < 4; ++n)
                    acc[m][n] = fmaf(av[m], bv[n], acc[m][n]);
        }
        __syncthreads();
    }
    int li[4], lj[4]; float ni[4], nj[4];
    #pragma unroll
    for (int m = 0; m < 4; ++m) {
        int gi = row0 + ty * 4 + m; li[m] = labels[gi]; ni[m] = norms[gi];
    }
    #pragma unroll
    for (int n = 0; n < 4; ++n) {
        int gj = col0 + tx * 4 + n; lj[n] = labels[gj]; nj[n] = norms[gj];
    }
    #pragma unroll
    for (int m = 0; m < 4; ++m) {
        float pmax = 0.0f;
        float nmin = __uint_as_float(0x7f800000u);
        #pragma unroll
        for (int n = 0; n < 4; ++n) {
            float sq = fmaxf(ni[m] + nj[n] - 2.0f * acc[m][n], 0.0f);
            if (li[m] == lj[n]) pmax = fmaxf(pmax, sq);
            else                nmin = fminf(nmin, sq);
        }
        #pragma unroll
        for (int o = 8; o; o >>= 1) {
            pmax = fmaxf(pmax, __shfl_xor(pmax, o));
            nmin = fminf(nmin, __shfl_xor(nmin, o));
        }
        if (tx == 0) {
            int gi = row0 + ty * 4 + m;
            atomicMax(&hp[gi], __float_as_uint(pmax));
            atomicMin(&hn[gi], __float_as_uint(nmin));
        }
    }
}

// ---------------- finalize: hist in LDS + per-row loss + full reduce ----------------
__global__ __launch_bounds__(1024) void finalize_kernel(
        const unsigned* __restrict__ hp, const unsigned* __restrict__ hn,
        const int* __restrict__ labels, float* __restrict__ out) {
    __shared__ int hist[256];
    __shared__ float wsum[16];
    int t = threadIdx.x;
    if (t < 256) hist[t] = 0;
    __syncthreads();
    int4 lab = ((const int4*)labels)[t];
    atomicAdd(&hist[lab.x], 1); atomicAdd(&hist[lab.y], 1);
    atomicAdd(&hist[lab.z], 1); atomicAdd(&hist[lab.w], 1);
    __syncthreads();
    uint4 hp4 = ((const uint4*)hp)[t];
    uint4 hn4 = ((const uint4*)hn)[t];
    int      lv[4]  = {lab.x, lab.y, lab.z, lab.w};
    unsigned hpv[4] = {hp4.x, hp4.y, hp4.z, hp4.w};
    unsigned hnv[4] = {hn4.x, hn4.y, hn4.z, hn4.w};
    float v = 0.f;
    #pragma unroll
    for (int j = 0; j < 4; ++j) {
        float hpd = sqrtf(__uint_as_float(hpv[j]));
        float hnd = sqrtf(__uint_as_float(hnv[j]));   // may be +inf
        if (hist[lv[j]] > 1) v += fmaxf(hpd - hnd + MARGIN, 0.f);
    }
    #pragma unroll
    for (int o = 32; o; o >>= 1) v += __shfl_xor(v, o);
    int lane = t & 63, wv = t >> 6;
    if (lane == 0) wsum[wv] = v;
    __syncthreads();
    if (t == 0) {
        float s = 0.f;
        #pragma unroll
        for (int i = 0; i < 16; ++i) s += wsum[i];
        out[0] = s / (float)NROWS;
    }
}

extern "C" void kernel_launch(void* const* d_in, const int* in_sizes, int n_in,
                              void* d_out, int out_size, void* d_ws, size_t ws_size,
                              hipStream_t stream) {
    const float* X      = (const float*)d_in[0];
    const int*   labels = (const int*)d_in[1];
    float* ws = (float*)d_ws;
    // ws (floats): norms[4096] | hp[4096] | hn[4096] | pad -> 64KB | Xh (4MB)
    float*    norms = ws;
    unsigned* hp    = (unsigned*)(ws + 4096);
    unsigned* hn    = (unsigned*)(ws + 8192);
    f16*      Xh    = (f16*)((char*)d_ws + 65536);
    float*    out   = (float*)d_out;

    const size_t need = 65536 + (size_t)NROWS * DIM * sizeof(f16);

    hipLaunchKernelGGL(norms_init_kernel, dim3(NROWS/4), dim3(256), 0, stream, X, norms, hp, hn);
    if (ws_size >= need) {
        hipLaunchKernelGGL(convert_kernel,   dim3(1024), dim3(256), 0, stream, X, Xh);
        hipLaunchKernelGGL(mfma_dist_kernel, dim3(528),  dim3(256), 0, stream, Xh, labels, norms, hp, hn);
    } else {
        hipLaunchKernelGGL(dist_fp32_kernel, dim3(64, 64), dim3(256), 0, stream, X, labels, norms, hp, hn);
    }
    hipLaunchKernelGGL(finalize_kernel, dim3(1), dim3(1024), 0, stream, hp, hn, labels, out);
}

// Round 6
// 33.936 us; speedup vs baseline: 1.8847x; 1.1635x over previous
//
#include <hip/hip_runtime.h>

#define NROWS 4096
#define DIM   512
#define MARGIN 0.3f

typedef _Float16 f16;
typedef _Float16 f16x8 __attribute__((ext_vector_type(8)));
typedef float    f32x4 __attribute__((ext_vector_type(4)));

// ---------------- prep: norms + fp32->fp16 tiled convert + hp/hn init ----------------
// Xh layout: tile (R,K0), R=row/128 in [0,32), K0=k/32 in [0,16).
// Tile = 512 units of 16B: unit u = rg*64 + c*16 + r (rg=(row%128)/16, r=row%16)
// element (row, k=K0*32+c*8+j) at half index (tile*512+u)*8 + j.
__global__ void prep_kernel(const float* __restrict__ X,
                            float* __restrict__ norms, f16* __restrict__ Xh,
                            unsigned* __restrict__ hp, unsigned* __restrict__ hn) {
    int t = threadIdx.x;
    int wave = t >> 6, lane = t & 63;
    int row  = blockIdx.x * 4 + wave;
    const float4* p = (const float4*)(X + (size_t)row * DIM + lane * 8);
    float4 a = p[0], b = p[1];
    float s = a.x*a.x + a.y*a.y + a.z*a.z + a.w*a.w
            + b.x*b.x + b.y*b.y + b.z*b.z + b.w*b.w;
    #pragma unroll
    for (int o = 32; o; o >>= 1) s += __shfl_xor(s, o);
    if (lane == 0) norms[row] = s;

    f16x8 h;
    h[0] = (f16)a.x; h[1] = (f16)a.y; h[2] = (f16)a.z; h[3] = (f16)a.w;
    h[4] = (f16)b.x; h[5] = (f16)b.y; h[6] = (f16)b.z; h[7] = (f16)b.w;
    int K0 = lane >> 2, c = lane & 3;
    int R = row >> 7, rw = row & 127, rg = rw >> 4, r = rw & 15;
    size_t unit = (size_t)(R * 16 + K0) * 512 + rg * 64 + c * 16 + r;
    *(f16x8*)(Xh + unit * 8) = h;

    int g = blockIdx.x * 256 + t;
    if (g < NROWS) { hp[g] = 0u; hn[g] = 0x7f800000u; }
}

__device__ inline void gload_lds16(const f16* g, f16* l) {
    __builtin_amdgcn_global_load_lds(
        (const __attribute__((address_space(1))) void*)g,
        (__attribute__((address_space(3))) void*)l, 16, 0, 0);
}

// stage one 128x32 A-tile + B-tile pair into buf; wave w covers units [qb, qb+256)
__device__ inline void stage_tile(const f16* __restrict__ At, const f16* __restrict__ Bt,
                                  f16* buf, int qb, int lane) {
    const f16* base = (qb < 512) ? (At + (size_t)qb * 8) : (Bt + (size_t)(qb - 512) * 8);
    #pragma unroll
    for (int c2 = 0; c2 < 4; ++c2)
        gload_lds16(base + (size_t)(c2 * 64 + lane) * 8, buf + (size_t)(qb + c2 * 64) * 8);
}

// ---------------- MFMA fused GEMM + masked row/col max-min ----------------
// Lower-triangle grid (by <= bx); 128x128 tile, 4 waves. Triple-buffered LDS,
// ONE barrier per K-step, counted vmcnt (4 steady, 0 only at the last step).
// Step kt: {vmcnt(4): own tile-kt loads done} -> barrier (all waves' kt loads
// landed; slot (kt+2)%3 fully consumed at step kt-1) -> stage tile kt+2 into
// that slot -> ds_read tile kt -> 16 MFMA. Loads get ~2 steps of slack.
__global__ __launch_bounds__(256, 3) void mfma_dist_kernel(
        const f16* __restrict__ Xh, const int* __restrict__ labels,
        const float* __restrict__ norms,
        unsigned* __restrict__ hp, unsigned* __restrict__ hn) {
    __shared__ __align__(16) f16 S[3 * 8192];

    const int t    = threadIdx.x;
    const int lane = t & 63, w = t >> 6;
    const int l15  = lane & 15, l4 = lane >> 4;

    // XCD chunk swizzle: 528 = 8 * 66 exactly -> bijective remap so each XCD
    // gets a contiguous run of triangle ids (panel working set fits its L2).
    int bthw = blockIdx.x;
    int bt = (bthw & 7) * 66 + (bthw >> 3);

    // linear bt -> (by <= bx)
    int bx = (int)((sqrtf(8.0f * bt + 1.0f) - 1.0f) * 0.5f);
    while ((bx + 1) * (bx + 2) / 2 <= bt) ++bx;
    while (bx * (bx + 1) / 2 > bt) --bx;
    int by = bt - bx * (bx + 1) / 2;

    const int wr = w >> 1, wc = w & 1;
    const int qb = w * 256;

    const f16* Abase = Xh + (size_t)(by * 16) * 4096;
    const f16* Bbase = Xh + (size_t)(bx * 16) * 4096;

    f32x4 zero = {0.f, 0.f, 0.f, 0.f};
    f32x4 acc[4][4];
    #pragma unroll
    for (int m = 0; m < 4; ++m)
        #pragma unroll
        for (int n = 0; n < 4; ++n) acc[m][n] = zero;

    // prologue: tiles 0,1 in flight (8 loads/wave)
    stage_tile(Abase,        Bbase,        S,        qb, lane);
    stage_tile(Abase + 4096, Bbase + 4096, S + 8192, qb, lane);
    __builtin_amdgcn_sched_barrier(0);

    #pragma unroll
    for (int kt = 0; kt < 16; ++kt) {
        f16* cur = S + (kt % 3) * 8192;
        // own tile-kt loads (oldest 4) done; keep tile kt+1 in flight
        if (kt == 15) asm volatile("s_waitcnt vmcnt(0)" ::: "memory");
        else          asm volatile("s_waitcnt vmcnt(4)" ::: "memory");
        __builtin_amdgcn_sched_barrier(0);
        __builtin_amdgcn_s_barrier();      // all waves' tile-kt data in LDS
        __builtin_amdgcn_sched_barrier(0);

        if (kt + 2 < 16)                   // slot (kt+2)%3 was consumed at kt-1
            stage_tile(Abase + (size_t)(kt + 2) * 4096,
                       Bbase + (size_t)(kt + 2) * 4096,
                       S + ((kt + 2) % 3) * 8192, qb, lane);
        __builtin_amdgcn_sched_barrier(0);

        f16x8 af[4], bf[4];
        #pragma unroll
        for (int m = 0; m < 4; ++m)
            af[m] = *(const f16x8*)&cur[(size_t)((wr * 4 + m) * 64 + l4 * 16 + l15) * 8];
        #pragma unroll
        for (int n = 0; n < 4; ++n)
            bf[n] = *(const f16x8*)&cur[(size_t)(512 + (wc * 4 + n) * 64 + l4 * 16 + l15) * 8];
        #pragma unroll
        for (int m = 0; m < 4; ++m)
            #pragma unroll
            for (int n = 0; n < 4; ++n)
                acc[m][n] = __builtin_amdgcn_mfma_f32_16x16x32_f16(af[m], bf[n], acc[m][n], 0, 0, 0);
        __builtin_amdgcn_sched_barrier(0);
    }

    // ---- epilogue: sq = ni + nj - 2*dot, masked row & col reduce ----
    const int wrow = by * 128 + wr * 64;
    const int wcol = bx * 128 + wc * 64;
    const float FINF = __uint_as_float(0x7f800000u);

    int lj[4]; float nj[4];
    #pragma unroll
    for (int n = 0; n < 4; ++n) {
        int gc = wcol + n * 16 + l15; lj[n] = labels[gc]; nj[n] = norms[gc];
    }
    int li[16]; float ni[16];
    #pragma unroll
    for (int m = 0; m < 4; ++m)
        #pragma unroll
        for (int r = 0; r < 4; ++r) {
            int gr = wrow + m * 16 + l4 * 4 + r;
            li[m * 4 + r] = labels[gr]; ni[m * 4 + r] = norms[gr];
        }

    float cp[4], cn[4];
    #pragma unroll
    for (int n = 0; n < 4; ++n) { cp[n] = 0.f; cn[n] = FINF; }

    #pragma unroll
    for (int m = 0; m < 4; ++m) {
        #pragma unroll
        for (int r = 0; r < 4; ++r) {
            float rp = 0.f, rn = FINF;
            #pragma unroll
            for (int n = 0; n < 4; ++n) {
                float sq = fmaxf(fmaf(-2.f, acc[m][n][r], ni[m * 4 + r] + nj[n]), 0.f);
                bool same = (li[m * 4 + r] == lj[n]);
                rp = same ? fmaxf(rp, sq) : rp;
                rn = same ? rn : fminf(rn, sq);
                cp[n] = same ? fmaxf(cp[n], sq) : cp[n];
                cn[n] = same ? cn[n] : fminf(cn[n], sq);
            }
            #pragma unroll
            for (int o = 8; o; o >>= 1) {
                rp = fmaxf(rp, __shfl_xor(rp, o));
                rn = fminf(rn, __shfl_xor(rn, o));
            }
            if (l15 == 0) {
                int gr = wrow + m * 16 + l4 * 4 + r;
                atomicMax(&hp[gr], __float_as_uint(rp));
                atomicMin(&hn[gr], __float_as_uint(rn));
            }
        }
    }
    #pragma unroll
    for (int n = 0; n < 4; ++n) {
        float p = cp[n], q = cn[n];
        p = fmaxf(p, __shfl_xor(p, 16)); q = fminf(q, __shfl_xor(q, 16));
        p = fmaxf(p, __shfl_xor(p, 32)); q = fminf(q, __shfl_xor(q, 32));
        if (l4 == 0) {
            int gc = wcol + n * 16 + l15;
            atomicMax(&hp[gc], __float_as_uint(p));
            atomicMin(&hn[gc], __float_as_uint(q));
        }
    }
}

// ---------------- fp32 fallback path (ws too small for Xh) ----------------
__global__ void norms_init_kernel(const float* __restrict__ X,
                                  float* __restrict__ norms,
                                  unsigned* __restrict__ hp, unsigned* __restrict__ hn) {
    int wave = threadIdx.x >> 6;
    int lane = threadIdx.x & 63;
    int row  = blockIdx.x * 4 + wave;
    const float4* xr = (const float4*)(X + (size_t)row * DIM);
    float4 a = xr[lane];
    float4 b = xr[lane + 64];
    float s = a.x*a.x + a.y*a.y + a.z*a.z + a.w*a.w
            + b.x*b.x + b.y*b.y + b.z*b.z + b.w*b.w;
    #pragma unroll
    for (int o = 32; o; o >>= 1) s += __shfl_xor(s, o);
    if (lane == 0) norms[row] = s;
    int g = blockIdx.x * 256 + threadIdx.x;
    if (g < NROWS) { hp[g] = 0u; hn[g] = 0x7f800000u; }
}

#define BK  32
#define PAD 68
__global__ __launch_bounds__(256) void dist_fp32_kernel(
        const float* __restrict__ X, const int* __restrict__ labels,
        const float* __restrict__ norms,
        unsigned* __restrict__ hp, unsigned* __restrict__ hn) {
    __shared__ __align__(16) float As[BK][PAD];
    __shared__ __align__(16) float Bs[BK][PAD];
    const int t  = threadIdx.x;
    const int tx = t & 15, ty = t >> 4;
    const int row0 = blockIdx.y * 64, col0 = blockIdx.x * 64;

    float acc[4][4] = {};
    for (int k0 = 0; k0 < DIM; k0 += BK) {
        #pragma unroll
        for (int l = 0; l < 2; ++l) {
            int idx = t + l * 256;
            int r = idx >> 3, fc = idx & 7;
            float4 va = *(const float4*)(X + (size_t)(row0 + r) * DIM + k0 + fc * 4);
            float4 vb = *(const float4*)(X + (size_t)(col0 + r) * DIM + k0 + fc * 4);
            As[fc*4+0][r] = va.x; As[fc*4+1][r] = va.y;
            As[fc*4+2][r] = va.z; As[fc*4+3][r] = va.w;
            Bs[fc*4+0][r] = vb.x; Bs[fc*4+1][r] = vb.y;
            Bs[fc*4+2][r] = vb.z; Bs[fc*4+3][r] = vb.w;
        }
        __syncthreads();
        #pragma unroll
        for (int kk = 0; kk < BK; ++kk) {
            float4 a = *(const float4*)&As[kk][ty * 4];
            float4 b = *(const float4*)&Bs[kk][tx * 4];
            float av[4] = {a.x, a.y, a.z, a.w};
            float bv[4] = {b.x, b.y, b.z, b.w};
            #pragma unroll
            for (int m = 0; m < 4; ++m)
                #pragma unroll
                for (int n = 0; n < 4; ++n)
                    acc[m][n] = fmaf(av[m], bv[n], acc[m][n]);
        }
        __syncthreads();
    }
    int li[4], lj[4]; float ni[4], nj[4];
    #pragma unroll
    for (int m = 0; m < 4; ++m) {
        int gi = row0 + ty * 4 + m; li[m] = labels[gi]; ni[m] = norms[gi];
    }
    #pragma unroll
    for (int n = 0; n < 4; ++n) {
        int gj = col0 + tx * 4 + n; lj[n] = labels[gj]; nj[n] = norms[gj];
    }
    #pragma unroll
    for (int m = 0; m < 4; ++m) {
        float pmax = 0.0f;
        float nmin = __uint_as_float(0x7f800000u);
        #pragma unroll
        for (int n = 0; n < 4; ++n) {
            float sq = fmaxf(ni[m] + nj[n] - 2.0f * acc[m][n], 0.0f);
            if (li[m] == lj[n]) pmax = fmaxf(pmax, sq);
            else                nmin = fminf(nmin, sq);
        }
        #pragma unroll
        for (int o = 8; o; o >>= 1) {
            pmax = fmaxf(pmax, __shfl_xor(pmax, o));
            nmin = fminf(nmin, __shfl_xor(nmin, o));
        }
        if (tx == 0) {
            int gi = row0 + ty * 4 + m;
            atomicMax(&hp[gi], __float_as_uint(pmax));
            atomicMin(&hn[gi], __float_as_uint(nmin));
        }
    }
}

// ---------------- finalize: hist in LDS + per-row loss + full reduce ----------------
__global__ __launch_bounds__(1024) void finalize_kernel(
        const unsigned* __restrict__ hp, const unsigned* __restrict__ hn,
        const int* __restrict__ labels, float* __restrict__ out) {
    __shared__ int hist[256];
    __shared__ float wsum[16];
    int t = threadIdx.x;
    if (t < 256) hist[t] = 0;
    __syncthreads();
    int4 lab = ((const int4*)labels)[t];
    atomicAdd(&hist[lab.x], 1); atomicAdd(&hist[lab.y], 1);
    atomicAdd(&hist[lab.z], 1); atomicAdd(&hist[lab.w], 1);
    __syncthreads();
    uint4 hp4 = ((const uint4*)hp)[t];
    uint4 hn4 = ((const uint4*)hn)[t];
    int      lv[4]  = {lab.x, lab.y, lab.z, lab.w};
    unsigned hpv[4] = {hp4.x, hp4.y, hp4.z, hp4.w};
    unsigned hnv[4] = {hn4.x, hn4.y, hn4.z, hn4.w};
    float v = 0.f;
    #pragma unroll
    for (int j = 0; j < 4; ++j) {
        float hpd = sqrtf(__uint_as_float(hpv[j]));
        float hnd = sqrtf(__uint_as_float(hnv[j]));   // may be +inf
        if (hist[lv[j]] > 1) v += fmaxf(hpd - hnd + MARGIN, 0.f);
    }
    #pragma unroll
    for (int o = 32; o; o >>= 1) v += __shfl_xor(v, o);
    int lane = t & 63, wv = t >> 6;
    if (lane == 0) wsum[wv] = v;
    __syncthreads();
    if (t == 0) {
        float s = 0.f;
        #pragma unroll
        for (int i = 0; i < 16; ++i) s += wsum[i];
        out[0] = s / (float)NROWS;
    }
}

extern "C" void kernel_launch(void* const* d_in, const int* in_sizes, int n_in,
                              void* d_out, int out_size, void* d_ws, size_t ws_size,
                              hipStream_t stream) {
    const float* X      = (const float*)d_in[0];
    const int*   labels = (const int*)d_in[1];
    float* ws = (float*)d_ws;
    // ws (floats): norms[4096] | hp[4096] | hn[4096] | pad -> 64KB | Xh (4MB)
    float*    norms = ws;
    unsigned* hp    = (unsigned*)(ws + 4096);
    unsigned* hn    = (unsigned*)(ws + 8192);
    f16*      Xh    = (f16*)((char*)d_ws + 65536);
    float*    out   = (float*)d_out;

    const size_t need = 65536 + (size_t)NROWS * DIM * sizeof(f16);

    if (ws_size >= need) {
        hipLaunchKernelGGL(prep_kernel,      dim3(NROWS/4), dim3(256), 0, stream,
                           X, norms, Xh, hp, hn);
        hipLaunchKernelGGL(mfma_dist_kernel, dim3(528),     dim3(256), 0, stream,
                           Xh, labels, norms, hp, hn);
    } else {
        hipLaunchKernelGGL(norms_init_kernel, dim3(NROWS/4), dim3(256), 0, stream, X, norms, hp, hn);
        hipLaunchKernelGGL(dist_fp32_kernel,  dim3(64, 64),  dim3(256), 0, stream, X, labels, norms, hp, hn);
    }
    hipLaunchKernelGGL(finalize_kernel, dim3(1), dim3(1024), 0, stream, hp, hn, labels, out);
}